// Round 1
// baseline (701.784 us; speedup 1.0000x reference)
//
#include <hip/hip_runtime.h>
#include <cstdint>

// ---------------------------------------------------------------------------
// 2-layer GCN (PyG GCNConv semantics, add_self_loops=True, sym norm).
// N = 100000 nodes, E = 3.2M edges, F_IN=16, F_HID=32.
//
// Pipeline:
//   deg[c]   = sum_e ew[e] [c=col[e]]          (atomicAdd; self-loop folded as +1)
//   dis[i]   = rsqrt(deg[i]+1)
//   xw1      = x @ W1^T                        (fused with dis)
//   agg1[c] += xw1[r] * dis[r]*ew*dis[c]       (edge scatter, atomics)
//   h        = relu(agg1 + xw1*dis^2 + b1)     (self-loop + bias + relu)
//   xw2      = h @ W2^T                        (fused with epilogue 1)
//   agg2[c] += xw2[r] * dis[r]*ew*dis[c]       (edge scatter, atomics)
//   out      = agg2 + xw2*dis^2 + b2
// ---------------------------------------------------------------------------

__global__ void deg_kernel(const int* __restrict__ col,
                           const float* __restrict__ ew,
                           float* __restrict__ deg, int E) {
    int e = blockIdx.x * blockDim.x + threadIdx.x;
    if (e < E) atomicAdd(&deg[col[e]], ew[e]);
}

// dis = rsqrt(deg+1); xw1 = x @ W1^T   (W1: [32,16] row-major)
__global__ void dis_xw1_kernel(const float* __restrict__ x,
                               const float* __restrict__ W1,
                               const float* __restrict__ deg,
                               float* __restrict__ dis,
                               float* __restrict__ xw1,   // [N,32]
                               int N) {
    __shared__ float sW[512];
    for (int t = threadIdx.x; t < 512; t += blockDim.x) sW[t] = W1[t];
    __syncthreads();
    int i = blockIdx.x * blockDim.x + threadIdx.x;
    if (i >= N) return;

    float d = 1.0f / sqrtf(deg[i] + 1.0f);   // deg includes +1 self-loop -> always > 0
    dis[i] = d;

    float xr[16];
#pragma unroll
    for (int k = 0; k < 4; ++k) {
        float4 v = ((const float4*)(x + (size_t)i * 16))[k];
        xr[4*k+0] = v.x; xr[4*k+1] = v.y; xr[4*k+2] = v.z; xr[4*k+3] = v.w;
    }
    float* outp = xw1 + (size_t)i * 32;
#pragma unroll
    for (int o = 0; o < 32; ++o) {
        float acc = 0.f;
#pragma unroll
        for (int k = 0; k < 16; ++k) acc += xr[k] * sW[o*16 + k];
        outp[o] = acc;
    }
}

// One thread per (edge, feature). F is 32 or 16 (power of 2).
template <int F>
__global__ void scatter_kernel(const int* __restrict__ row,
                               const int* __restrict__ col,
                               const float* __restrict__ ew,
                               const float* __restrict__ dis,
                               const float* __restrict__ src,  // [N,F]
                               float* __restrict__ dst,        // [N,F]
                               int E) {
    unsigned int gid = blockIdx.x * blockDim.x + threadIdx.x;
    int e = (int)(gid / F);
    int f = (int)(gid & (F - 1));
    if (e >= E) return;
    int r = row[e];
    int c = col[e];
    float w = dis[r] * ew[e] * dis[c];
    atomicAdd(&dst[(size_t)c * F + f], src[(size_t)r * F + f] * w);
}

// h = relu(agg1 + xw1*dis^2 + b1); xw2 = h @ W2^T   (W2: [16,32] row-major)
__global__ void epi1_kernel(const float* __restrict__ agg1,  // [N,32]
                            const float* __restrict__ xw1,   // [N,32]
                            const float* __restrict__ dis,
                            const float* __restrict__ b1,    // [32]
                            const float* __restrict__ W2,    // [16,32]
                            float* __restrict__ xw2,         // [N,16]
                            int N) {
    __shared__ float sW[512];
    __shared__ float sb[32];
    for (int t = threadIdx.x; t < 512; t += blockDim.x) sW[t] = W2[t];
    if (threadIdx.x < 32) sb[threadIdx.x] = b1[threadIdx.x];
    __syncthreads();
    int i = blockIdx.x * blockDim.x + threadIdx.x;
    if (i >= N) return;

    float d2 = dis[i] * dis[i];
    float h[32];
#pragma unroll
    for (int k = 0; k < 8; ++k) {
        float4 a = ((const float4*)(agg1 + (size_t)i * 32))[k];
        float4 s = ((const float4*)(xw1 + (size_t)i * 32))[k];
        h[4*k+0] = fmaxf(a.x + s.x * d2 + sb[4*k+0], 0.f);
        h[4*k+1] = fmaxf(a.y + s.y * d2 + sb[4*k+1], 0.f);
        h[4*k+2] = fmaxf(a.z + s.z * d2 + sb[4*k+2], 0.f);
        h[4*k+3] = fmaxf(a.w + s.w * d2 + sb[4*k+3], 0.f);
    }
    float* outp = xw2 + (size_t)i * 16;
#pragma unroll
    for (int o = 0; o < 16; ++o) {
        float acc = 0.f;
#pragma unroll
        for (int k = 0; k < 32; ++k) acc += h[k] * sW[o*32 + k];
        outp[o] = acc;
    }
}

__global__ void epi2_kernel(const float* __restrict__ agg2,  // [N,16]
                            const float* __restrict__ xw2,   // [N,16]
                            const float* __restrict__ dis,
                            const float* __restrict__ b2,    // [16]
                            float* __restrict__ out,         // [N,16]
                            int N) {
    int gid = blockIdx.x * blockDim.x + threadIdx.x;
    if (gid >= N * 16) return;
    int i = gid >> 4;
    int f = gid & 15;
    out[gid] = agg2[gid] + xw2[gid] * dis[i] * dis[i] + b2[f];
}

extern "C" void kernel_launch(void* const* d_in, const int* in_sizes, int n_in,
                              void* d_out, int out_size, void* d_ws, size_t ws_size,
                              hipStream_t stream) {
    const float* x  = (const float*)d_in[0];
    const int*   ei = (const int*)d_in[1];   // [2, E] int32
    const float* ew = (const float*)d_in[2];
    const float* W1 = (const float*)d_in[3];
    const float* b1 = (const float*)d_in[4];
    const float* W2 = (const float*)d_in[5];
    const float* b2 = (const float*)d_in[6];
    float* out = (float*)d_out;

    const int N = in_sizes[0] / 16;
    const int E = in_sizes[2];
    const int* row = ei;
    const int* col = ei + E;

    float* ws   = (float*)d_ws;
    float* deg  = ws;                          // N
    float* dis  = deg + N;                     // N
    float* xw1  = dis + N;                     // N*32
    float* agg1 = xw1 + (size_t)N * 32;        // N*32
    float* xw2  = agg1 + (size_t)N * 32;       // N*16
    float* agg2 = xw2 + (size_t)N * 16;        // N*16

    hipMemsetAsync(deg,  0, (size_t)N * 4, stream);
    hipMemsetAsync(agg1, 0, (size_t)N * 32 * 4, stream);
    hipMemsetAsync(agg2, 0, (size_t)N * 16 * 4, stream);

    deg_kernel<<<(E + 255) / 256, 256, 0, stream>>>(col, ew, deg, E);
    dis_xw1_kernel<<<(N + 255) / 256, 256, 0, stream>>>(x, W1, deg, dis, xw1, N);

    {
        long long total = (long long)E * 32;
        scatter_kernel<32><<<(int)((total + 255) / 256), 256, 0, stream>>>(
            row, col, ew, dis, xw1, agg1, E);
    }
    epi1_kernel<<<(N + 255) / 256, 256, 0, stream>>>(agg1, xw1, dis, b1, W2, xw2, N);
    {
        long long total = (long long)E * 16;
        scatter_kernel<16><<<(int)((total + 255) / 256), 256, 0, stream>>>(
            row, col, ew, dis, xw2, agg2, E);
    }
    epi2_kernel<<<(N * 16 + 255) / 256, 256, 0, stream>>>(agg2, xw2, dis, b2, out, N);
}